// Round 6
// baseline (418.223 us; speedup 1.0000x reference)
//
#include <hip/hip_runtime.h>
#include <hip/hip_bf16.h>

// Mamba layer, MI355X. Inputs fp32; OUTPUT fp32 (round-5 probe proved output
// buffer is fp32 — bf16 spike at elem 0 was invisible; out_npz=4MB).
// B=4 SEQ=1024 DIM=256 DIN=512 DST=48 DTR=16 E=112. M = B*SEQ = 4096 rows.

constexpr int BSZ = 4, SEQ = 1024, DIM = 256, DIN = 512, DST = 48, DTR = 16, EPROJ = 112;
constexpr int M = BSZ * SEQ;            // 4096
constexpr int CH = 32, CL = 32;         // 32 chunks x 32 steps = 1024
constexpr int NBDS = BSZ * DIN * DST;   // 98304 independent scan streams

// ---------------- LayerNorm: x -> xn (fp32) ----------------
__global__ void k_ln(const float* __restrict__ x, const float* __restrict__ lnw,
                     const float* __restrict__ lnb, float* __restrict__ xn) {
    int m = blockIdx.x, t = threadIdx.x;     // 256 threads, one row per block
    float v = x[m * DIM + t];
    float s = v, s2 = v * v;
#pragma unroll
    for (int off = 32; off; off >>= 1) { s += __shfl_down(s, off); s2 += __shfl_down(s2, off); }
    __shared__ float ss[4], sq[4];
    int w = t >> 6;
    if ((t & 63) == 0) { ss[w] = s; sq[w] = s2; }
    __syncthreads();
    float tot = ss[0] + ss[1] + ss[2] + ss[3];
    float tq = sq[0] + sq[1] + sq[2] + sq[3];
    float mu = tot * (1.f / DIM);
    float var = tq * (1.f / DIM) - mu * mu;  // biased, matches jnp.var
    float rs = rsqrtf(var + 1e-5f);
    xn[m * DIM + t] = (v - mu) * rs * lnw[t] + lnb[t];
}

// ---------------- Generic tiled GEMM: out[m,n] = sum_k A[m,k]*W[n,k] ----------------
// A fp32 [M][KT] (rows contiguous), W fp32 [Ntot][KT]. 256 threads = 8 row-groups x 32 col-threads.
template <int MT, int KT, int NC>
__global__ void k_gemm(const float* __restrict__ A, const float* __restrict__ W,
                       float* __restrict__ outp, int Nvalid, int ldo) {
    constexpr int MR = MT / 8;
    __shared__ float As[MT * KT];
    const float* Ab = A + (size_t)blockIdx.x * (MT * KT);
    for (int i = threadIdx.x; i < MT * KT / 4; i += 256)
        ((float4*)As)[i] = ((const float4*)Ab)[i];
    __syncthreads();
    const int ty = threadIdx.x >> 5, tx = threadIdx.x & 31;
    const int r0 = ty * MR;
    const int c0 = blockIdx.y * (32 * NC) + tx * NC;
    float acc[MR][NC];
#pragma unroll
    for (int r = 0; r < MR; r++)
#pragma unroll
        for (int j = 0; j < NC; j++) acc[r][j] = 0.f;

    for (int k = 0; k < KT; k += 8) {
        float wf[NC][8];
#pragma unroll
        for (int j = 0; j < NC; j++) {
            int cc = c0 + j;
            if (cc < Nvalid) {
                float4 w0 = *(const float4*)(W + (size_t)cc * KT + k);
                float4 w1 = *(const float4*)(W + (size_t)cc * KT + k + 4);
                wf[j][0] = w0.x; wf[j][1] = w0.y; wf[j][2] = w0.z; wf[j][3] = w0.w;
                wf[j][4] = w1.x; wf[j][5] = w1.y; wf[j][6] = w1.z; wf[j][7] = w1.w;
            } else {
#pragma unroll
                for (int q = 0; q < 8; q++) wf[j][q] = 0.f;
            }
        }
#pragma unroll
        for (int r = 0; r < MR; r++) {
            const float* ap = &As[(r0 + r) * KT + k];
            float4 a0 = *(const float4*)ap;
            float4 a1 = *(const float4*)(ap + 4);
#pragma unroll
            for (int j = 0; j < NC; j++) {
                float t0 = fmaf(a0.x, wf[j][0], fmaf(a0.y, wf[j][1], fmaf(a0.z, wf[j][2], a0.w * wf[j][3])));
                float t1 = fmaf(a1.x, wf[j][4], fmaf(a1.y, wf[j][5], fmaf(a1.z, wf[j][6], a1.w * wf[j][7])));
                acc[r][j] += t0 + t1;
            }
        }
    }
#pragma unroll
    for (int r = 0; r < MR; r++) {
        int m = blockIdx.x * MT + r0 + r;
#pragma unroll
        for (int j = 0; j < NC; j++) {
            int cc = c0 + j;
            if (cc < Nvalid) outp[(size_t)m * ldo + cc] = acc[r][j];
        }
    }
}

// ---------------- causal depthwise conv(4) + bias + silu: xz[:, :512] -> u ----------------
__global__ void k_conv(const float* __restrict__ xz, const float* __restrict__ cw,
                       const float* __restrict__ cb, float* __restrict__ u) {
    int idx = blockIdx.x * 256 + threadIdx.x;     // [0, M*DIN)
    int d = idx & (DIN - 1);
    int m = idx >> 9;
    int n = m & (SEQ - 1);
    float4 w = *(const float4*)(cw + d * 4);
    float acc = cb[d] + xz[(size_t)m * (2 * DIN) + d] * w.w;
    if (n >= 1) acc += xz[(size_t)(m - 1) * (2 * DIN) + d] * w.z;
    if (n >= 2) acc += xz[(size_t)(m - 2) * (2 * DIN) + d] * w.y;
    if (n >= 3) acc += xz[(size_t)(m - 3) * (2 * DIN) + d] * w.x;
    u[idx] = acc / (1.f + __expf(-acc));          // silu
}

// ---------------- dt = softplus(dtr @ dtw^T + dtb) ----------------
__global__ void k_dt(const float* __restrict__ xdbl, const float* __restrict__ dtw,
                     const float* __restrict__ dtb, float* __restrict__ dt) {
    __shared__ float r[DTR];
    int m = blockIdx.x, t = threadIdx.x;
    if (t < DTR) r[t] = xdbl[(size_t)m * EPROJ + t];
    __syncthreads();
    for (int d = t; d < DIN; d += 256) {
        const float* wp = dtw + (size_t)d * DTR;
        float acc = dtb[d];
#pragma unroll
        for (int q = 0; q < DTR; q++) acc = fmaf(r[q], wp[q], acc);
        dt[(size_t)m * DIN + d] = (acc > 20.f) ? acc : log1pf(__expf(acc));
    }
}

// ---------------- scan pass1: per-chunk (P = prod dA, H = local scan end) ----------------
__global__ __launch_bounds__(256, 1) void k_scan1(const float* __restrict__ dt, const float* __restrict__ u,
                                                  const float* __restrict__ xdbl, const float* __restrict__ alog,
                                                  float* __restrict__ P, float* __restrict__ H) {
    int c = blockIdx.x & (CH - 1), b = blockIdx.x >> 5;
    int d = blockIdx.y * 256 + threadIdx.x;
    float A[DST];
#pragma unroll
    for (int q = 0; q < 12; q++) {
        float4 v = ((const float4*)(alog + (size_t)d * DST))[q];
        A[4 * q] = -__expf(v.x); A[4 * q + 1] = -__expf(v.y);
        A[4 * q + 2] = -__expf(v.z); A[4 * q + 3] = -__expf(v.w);
    }
    __shared__ float Bc[CL][DST];
    int m0 = b * SEQ + c * CL;
    for (int i = threadIdx.x; i < CL * DST; i += 256)
        Bc[i / DST][i % DST] = xdbl[(size_t)(m0 + i / DST) * EPROJ + DTR + (i % DST)];
    __syncthreads();
    float Ps[DST], Hs[DST];
#pragma unroll
    for (int s = 0; s < DST; s++) { Ps[s] = 1.f; Hs[s] = 0.f; }
    for (int nl = 0; nl < CL; nl++) {
        size_t m = m0 + nl;
        float dtv = dt[m * DIN + d];
        float dtu = dtv * u[m * DIN + d];
#pragma unroll
        for (int s = 0; s < DST; s++) {
            float dA = __expf(dtv * A[s]);
            Ps[s] *= dA;
            Hs[s] = fmaf(dA, Hs[s], dtu * Bc[nl][s]);
        }
    }
    size_t base = (size_t)c * NBDS + ((size_t)(b * DIN + d)) * DST;
#pragma unroll
    for (int q = 0; q < 12; q++) {
        ((float4*)(P + base))[q] = make_float4(Ps[4 * q], Ps[4 * q + 1], Ps[4 * q + 2], Ps[4 * q + 3]);
        ((float4*)(H + base))[q] = make_float4(Hs[4 * q], Hs[4 * q + 1], Hs[4 * q + 2], Hs[4 * q + 3]);
    }
}

// ---------------- scan pass2: carry scan across chunks; P[c] := state BEFORE chunk c ----------------
__global__ void k_scan2(float* __restrict__ P, const float* __restrict__ H) {
    size_t idx = (size_t)blockIdx.x * 256 + threadIdx.x;   // [0, NBDS)
    float car = 0.f;
    for (int c = 0; c < CH; c++) {
        size_t o = (size_t)c * NBDS + idx;
        float p = P[o], h = H[o];
        P[o] = car;
        car = fmaf(p, car, h);
    }
}

// ---------------- scan pass3: replay chunk from carry, fuse +u*D and *silu(z) ----------------
__global__ __launch_bounds__(256, 1) void k_scan3(const float* __restrict__ dt, const float* __restrict__ u,
                                                  const float* __restrict__ xdbl, const float* __restrict__ alog,
                                                  const float* __restrict__ carry, const float* __restrict__ xz,
                                                  const float* __restrict__ Dw, float* __restrict__ yc) {
    int c = blockIdx.x & (CH - 1), b = blockIdx.x >> 5;
    int d = blockIdx.y * 256 + threadIdx.x;
    float A[DST];
#pragma unroll
    for (int q = 0; q < 12; q++) {
        float4 v = ((const float4*)(alog + (size_t)d * DST))[q];
        A[4 * q] = -__expf(v.x); A[4 * q + 1] = -__expf(v.y);
        A[4 * q + 2] = -__expf(v.z); A[4 * q + 3] = -__expf(v.w);
    }
    __shared__ float Bc[CL][DST], Cc[CL][DST];
    int m0 = b * SEQ + c * CL;
    for (int i = threadIdx.x; i < CL * DST; i += 256) {
        int nl = i / DST, s = i % DST;
        size_t row = (size_t)(m0 + nl) * EPROJ;
        Bc[nl][s] = xdbl[row + DTR + s];
        Cc[nl][s] = xdbl[row + DTR + DST + s];
    }
    __syncthreads();
    float h[DST];
    size_t base = (size_t)c * NBDS + ((size_t)(b * DIN + d)) * DST;
#pragma unroll
    for (int q = 0; q < 12; q++) {
        float4 v = ((const float4*)(carry + base))[q];
        h[4 * q] = v.x; h[4 * q + 1] = v.y; h[4 * q + 2] = v.z; h[4 * q + 3] = v.w;
    }
    float Dv = Dw[d];
    for (int nl = 0; nl < CL; nl++) {
        size_t m = m0 + nl;
        float dtv = dt[m * DIN + d];
        float uv = u[m * DIN + d];
        float dtu = dtv * uv;
        float y = 0.f;
#pragma unroll
        for (int s = 0; s < DST; s++) {
            float dA = __expf(dtv * A[s]);
            h[s] = fmaf(dA, h[s], dtu * Bc[nl][s]);
            y = fmaf(h[s], Cc[nl][s], y);
        }
        float yv = fmaf(uv, Dv, y);
        float zv = xz[m * (2 * DIN) + DIN + d];
        float sz = zv / (1.f + __expf(-zv));
        yc[m * DIN + d] = yv * sz;
    }
}

extern "C" void kernel_launch(void* const* d_in, const int* in_sizes, int n_in,
                              void* d_out, int out_size, void* d_ws, size_t ws_size,
                              hipStream_t stream) {
    const float* x     = (const float*)d_in[0];
    const float* lnw   = (const float*)d_in[1];
    const float* lnb   = (const float*)d_in[2];
    const float* w_in  = (const float*)d_in[3];   // (1024, 256)
    const float* cw    = (const float*)d_in[4];   // (512, 4)
    const float* cb    = (const float*)d_in[5];
    const float* w_xp  = (const float*)d_in[6];   // (112, 512)
    const float* dtw   = (const float*)d_in[7];   // (512, 16)
    const float* dtb   = (const float*)d_in[8];
    const float* alog  = (const float*)d_in[9];   // (512, 48)
    const float* Dw    = (const float*)d_in[10];
    const float* w_out = (const float*)d_in[11];  // (256, 512)

    float* ws = (float*)d_ws;
    float* xn   = ws;                        // 4096*256
    float* xz   = xn + (size_t)M * DIM;      // 4096*1024
    float* u    = xz + (size_t)M * 2 * DIN;  // 4096*512
    float* xdbl = u + (size_t)M * DIN;       // 4096*112
    float* dt   = xdbl + (size_t)M * EPROJ;  // 4096*512
    float* P    = dt + (size_t)M * DIN;      // 32*98304
    float* Hy   = P + (size_t)CH * NBDS;     // 32*98304 (reused as gated-y after pass2)
    size_t need = ((size_t)(Hy - ws) + (size_t)CH * NBDS) * sizeof(float); // ~64.8 MB
    if (ws_size < need) return;              // fail visibly (zeros) if ws too small
    float* yc = Hy;                          // gated y, 4096*512 fp32

    k_ln<<<M, 256, 0, stream>>>(x, lnw, lnb, xn);
    k_gemm<32, 256, 2><<<dim3(M / 32, 1024 / 64), 256, 0, stream>>>(xn, w_in, xz, 1024, 1024);
    k_conv<<<M * DIN / 256, 256, 0, stream>>>(xz, cw, cb, u);
    k_gemm<16, 512, 4><<<dim3(M / 16, 1), 256, 0, stream>>>(u, w_xp, xdbl, EPROJ, EPROJ);
    k_dt<<<M, 256, 0, stream>>>(xdbl, dtw, dtb, dt);
    k_scan1<<<dim3(BSZ * CH, 2), 256, 0, stream>>>(dt, u, xdbl, alog, P, Hy);
    k_scan2<<<NBDS / 256, 256, 0, stream>>>(P, Hy);
    k_scan3<<<dim3(BSZ * CH, 2), 256, 0, stream>>>(dt, u, xdbl, alog, P, xz, Dw, yc);
    k_gemm<16, 512, 2><<<dim3(M / 16, 256 / 64), 256, 0, stream>>>(yc, w_out, (float*)d_out, 256, 256);
}

// Round 7
// 245.281 us; speedup vs baseline: 1.7051x; 1.7051x over previous
//
#include <hip/hip_runtime.h>
#include <hip/hip_bf16.h>

// Mamba layer, MI355X. Inputs fp32; OUTPUT fp32. Internal math fp32.
// Round 7: the three GEMMs moved to MFMA via split-bf16 (hh+hl+lh, ~2^-16 rel err).
// B=4 SEQ=1024 DIM=256 DIN=512 DST=48 DTR=16 E=112. M = B*SEQ = 4096 rows.

constexpr int BSZ = 4, SEQ = 1024, DIM = 256, DIN = 512, DST = 48, DTR = 16, EPROJ = 112;
constexpr int M = BSZ * SEQ;            // 4096
constexpr int CH = 32, CL = 32;         // 32 chunks x 32 steps = 1024
constexpr int NBDS = BSZ * DIN * DST;   // 98304 independent scan streams

using bfrag = __attribute__((ext_vector_type(8))) short;
using f32x4 = __attribute__((ext_vector_type(4))) float;
using us4   = __attribute__((ext_vector_type(4))) unsigned short;

static __device__ __forceinline__ unsigned short f2bf(float f) {
    union { float f; unsigned u; } v; v.f = f;
    unsigned r = v.u + 0x7fffu + ((v.u >> 16) & 1u);   // RTN-even
    return (unsigned short)(r >> 16);
}
static __device__ __forceinline__ float bf2f(unsigned short h) {
    union { unsigned u; float f; } v; v.u = (unsigned)h << 16;
    return v.f;
}

// ---------------- LayerNorm: x -> xn (fp32) ----------------
__global__ void k_ln(const float* __restrict__ x, const float* __restrict__ lnw,
                     const float* __restrict__ lnb, float* __restrict__ xn) {
    int m = blockIdx.x, t = threadIdx.x;     // 256 threads, one row per block
    float v = x[m * DIM + t];
    float s = v, s2 = v * v;
#pragma unroll
    for (int off = 32; off; off >>= 1) { s += __shfl_down(s, off); s2 += __shfl_down(s2, off); }
    __shared__ float ss[4], sq[4];
    int w = t >> 6;
    if ((t & 63) == 0) { ss[w] = s; sq[w] = s2; }
    __syncthreads();
    float tot = ss[0] + ss[1] + ss[2] + ss[3];
    float tq = sq[0] + sq[1] + sq[2] + sq[3];
    float mu = tot * (1.f / DIM);
    float var = tq * (1.f / DIM) - mu * mu;  // biased, matches jnp.var
    float rs = rsqrtf(var + 1e-5f);
    xn[m * DIM + t] = (v - mu) * rs * lnw[t] + lnb[t];
}

// ---------------- MFMA GEMM, split-bf16: out[m,n] = sum_k A[m,k]*W[n,k] ----------------
// A fp32 [Mtot][K], W fp32 [Ntot][K]. 256 threads = 4 waves in 2x2 wave-grid.
// Each wave computes (FM*16) x (FN*16); per k-tile (BK=32) does FM*FN*3 MFMAs.
template <int BM, int BN, int FM, int FN>
__global__ __launch_bounds__(256, 1) void k_gemm_mfma(
    const float* __restrict__ A, const float* __restrict__ W,
    float* __restrict__ outp, int K, int Nvalid, int ldo) {
    constexpr int BK = 32, BKP = 40;   // pad rows to 80B: 16B-aligned, uniform banks
    __shared__ __align__(16) unsigned short Ah[BM * BKP], Al[BM * BKP];
    __shared__ __align__(16) unsigned short Bh[BN * BKP], Bl[BN * BKP];
    const int tid = threadIdx.x;
    const int lane = tid & 63;
    const int w = tid >> 6;
    const int wm = w >> 1, wn = w & 1;
    const int bm0 = blockIdx.x * BM;
    const int bn0 = blockIdx.y * BN;

    f32x4 acc[FM][FN];
#pragma unroll
    for (int i = 0; i < FM; i++)
#pragma unroll
        for (int j = 0; j < FN; j++) acc[i][j] = f32x4{0.f, 0.f, 0.f, 0.f};

    for (int k0 = 0; k0 < K; k0 += BK) {
        // ---- stage A tile (BM x 32 fp32 -> hi/lo bf16 planes) ----
        for (int flat = tid * 4; flat < BM * BK; flat += 1024) {
            int r = flat >> 5, c = flat & 31;
            float4 v = *(const float4*)(A + (size_t)(bm0 + r) * K + k0 + c);
            us4 hi, lo;
            hi.x = f2bf(v.x); lo.x = f2bf(v.x - bf2f(hi.x));
            hi.y = f2bf(v.y); lo.y = f2bf(v.y - bf2f(hi.y));
            hi.z = f2bf(v.z); lo.z = f2bf(v.z - bf2f(hi.z));
            hi.w = f2bf(v.w); lo.w = f2bf(v.w - bf2f(hi.w));
            *(us4*)&Ah[r * BKP + c] = hi;
            *(us4*)&Al[r * BKP + c] = lo;
        }
        // ---- stage B tile (BN x 32 rows of W) ----
        for (int flat = tid * 4; flat < BN * BK; flat += 1024) {
            int r = flat >> 5, c = flat & 31;
            int gn = bn0 + r;
            float4 v = (gn < Nvalid) ? *(const float4*)(W + (size_t)gn * K + k0 + c)
                                     : float4{0.f, 0.f, 0.f, 0.f};
            us4 hi, lo;
            hi.x = f2bf(v.x); lo.x = f2bf(v.x - bf2f(hi.x));
            hi.y = f2bf(v.y); lo.y = f2bf(v.y - bf2f(hi.y));
            hi.z = f2bf(v.z); lo.z = f2bf(v.z - bf2f(hi.z));
            hi.w = f2bf(v.w); lo.w = f2bf(v.w - bf2f(hi.w));
            *(us4*)&Bh[r * BKP + c] = hi;
            *(us4*)&Bl[r * BKP + c] = lo;
        }
        __syncthreads();

        // ---- fragment loads: lane&15 = row(col), (lane>>4)*8 = k offset ----
        const int kcol = (lane >> 4) * 8;
        const int rsel = lane & 15;
        bfrag afh[FM], afl[FM], bfh[FN], bfl[FN];
#pragma unroll
        for (int i = 0; i < FM; i++) {
            int row = wm * (FM * 16) + i * 16 + rsel;
            afh[i] = *(const bfrag*)&Ah[row * BKP + kcol];
            afl[i] = *(const bfrag*)&Al[row * BKP + kcol];
        }
#pragma unroll
        for (int j = 0; j < FN; j++) {
            int col = wn * (FN * 16) + j * 16 + rsel;
            bfh[j] = *(const bfrag*)&Bh[col * BKP + kcol];
            bfl[j] = *(const bfrag*)&Bl[col * BKP + kcol];
        }
#pragma unroll
        for (int i = 0; i < FM; i++)
#pragma unroll
            for (int j = 0; j < FN; j++) {
                acc[i][j] = __builtin_amdgcn_mfma_f32_16x16x32_bf16(afh[i], bfh[j], acc[i][j], 0, 0, 0);
                acc[i][j] = __builtin_amdgcn_mfma_f32_16x16x32_bf16(afh[i], bfl[j], acc[i][j], 0, 0, 0);
                acc[i][j] = __builtin_amdgcn_mfma_f32_16x16x32_bf16(afl[i], bfh[j], acc[i][j], 0, 0, 0);
            }
        __syncthreads();
    }

    // ---- epilogue: C/D layout col=lane&15, row=(lane>>4)*4+reg ----
    const int crow = (lane >> 4) * 4;
    const int ccol = lane & 15;
#pragma unroll
    for (int i = 0; i < FM; i++)
#pragma unroll
        for (int j = 0; j < FN; j++) {
            int gn = bn0 + wn * (FN * 16) + j * 16 + ccol;
            if (gn < Nvalid) {
                int gm = bm0 + wm * (FM * 16) + i * 16 + crow;
#pragma unroll
                for (int r = 0; r < 4; r++)
                    outp[(size_t)(gm + r) * ldo + gn] = acc[i][j][r];
            }
        }
}

// ---------------- causal depthwise conv(4) + bias + silu: xz[:, :512] -> u ----------------
__global__ void k_conv(const float* __restrict__ xz, const float* __restrict__ cw,
                       const float* __restrict__ cb, float* __restrict__ u) {
    int idx = blockIdx.x * 256 + threadIdx.x;     // [0, M*DIN)
    int d = idx & (DIN - 1);
    int m = idx >> 9;
    int n = m & (SEQ - 1);
    float4 w = *(const float4*)(cw + d * 4);
    float acc = cb[d] + xz[(size_t)m * (2 * DIN) + d] * w.w;
    if (n >= 1) acc += xz[(size_t)(m - 1) * (2 * DIN) + d] * w.z;
    if (n >= 2) acc += xz[(size_t)(m - 2) * (2 * DIN) + d] * w.y;
    if (n >= 3) acc += xz[(size_t)(m - 3) * (2 * DIN) + d] * w.x;
    u[idx] = acc / (1.f + __expf(-acc));          // silu
}

// ---------------- dt = softplus(dtr @ dtw^T + dtb) ----------------
__global__ void k_dt(const float* __restrict__ xdbl, const float* __restrict__ dtw,
                     const float* __restrict__ dtb, float* __restrict__ dt) {
    __shared__ float r[DTR];
    int m = blockIdx.x, t = threadIdx.x;
    if (t < DTR) r[t] = xdbl[(size_t)m * EPROJ + t];
    __syncthreads();
    for (int d = t; d < DIN; d += 256) {
        const float* wp = dtw + (size_t)d * DTR;
        float acc = dtb[d];
#pragma unroll
        for (int q = 0; q < DTR; q++) acc = fmaf(r[q], wp[q], acc);
        dt[(size_t)m * DIN + d] = (acc > 20.f) ? acc : log1pf(__expf(acc));
    }
}

// ---------------- scan pass1: per-chunk (P = prod dA, H = local scan end) ----------------
__global__ __launch_bounds__(256, 1) void k_scan1(const float* __restrict__ dt, const float* __restrict__ u,
                                                  const float* __restrict__ xdbl, const float* __restrict__ alog,
                                                  float* __restrict__ P, float* __restrict__ H) {
    int c = blockIdx.x & (CH - 1), b = blockIdx.x >> 5;
    int d = blockIdx.y * 256 + threadIdx.x;
    float A[DST];
#pragma unroll
    for (int q = 0; q < 12; q++) {
        float4 v = ((const float4*)(alog + (size_t)d * DST))[q];
        A[4 * q] = -__expf(v.x); A[4 * q + 1] = -__expf(v.y);
        A[4 * q + 2] = -__expf(v.z); A[4 * q + 3] = -__expf(v.w);
    }
    __shared__ float Bc[CL][DST];
    int m0 = b * SEQ + c * CL;
    for (int i = threadIdx.x; i < CL * DST; i += 256)
        Bc[i / DST][i % DST] = xdbl[(size_t)(m0 + i / DST) * EPROJ + DTR + (i % DST)];
    __syncthreads();
    float Ps[DST], Hs[DST];
#pragma unroll
    for (int s = 0; s < DST; s++) { Ps[s] = 1.f; Hs[s] = 0.f; }
    for (int nl = 0; nl < CL; nl++) {
        size_t m = m0 + nl;
        float dtv = dt[m * DIN + d];
        float dtu = dtv * u[m * DIN + d];
#pragma unroll
        for (int s = 0; s < DST; s++) {
            float dA = __expf(dtv * A[s]);
            Ps[s] *= dA;
            Hs[s] = fmaf(dA, Hs[s], dtu * Bc[nl][s]);
        }
    }
    size_t base = (size_t)c * NBDS + ((size_t)(b * DIN + d)) * DST;
#pragma unroll
    for (int q = 0; q < 12; q++) {
        ((float4*)(P + base))[q] = make_float4(Ps[4 * q], Ps[4 * q + 1], Ps[4 * q + 2], Ps[4 * q + 3]);
        ((float4*)(H + base))[q] = make_float4(Hs[4 * q], Hs[4 * q + 1], Hs[4 * q + 2], Hs[4 * q + 3]);
    }
}

// ---------------- scan pass2: carry scan across chunks; P[c] := state BEFORE chunk c ----------------
__global__ void k_scan2(float* __restrict__ P, const float* __restrict__ H) {
    size_t idx = (size_t)blockIdx.x * 256 + threadIdx.x;   // [0, NBDS)
    float car = 0.f;
    for (int c = 0; c < CH; c++) {
        size_t o = (size_t)c * NBDS + idx;
        float p = P[o], h = H[o];
        P[o] = car;
        car = fmaf(p, car, h);
    }
}

// ---------------- scan pass3: replay chunk from carry, fuse +u*D and *silu(z) ----------------
__global__ __launch_bounds__(256, 1) void k_scan3(const float* __restrict__ dt, const float* __restrict__ u,
                                                  const float* __restrict__ xdbl, const float* __restrict__ alog,
                                                  const float* __restrict__ carry, const float* __restrict__ xz,
                                                  const float* __restrict__ Dw, float* __restrict__ yc) {
    int c = blockIdx.x & (CH - 1), b = blockIdx.x >> 5;
    int d = blockIdx.y * 256 + threadIdx.x;
    float A[DST];
#pragma unroll
    for (int q = 0; q < 12; q++) {
        float4 v = ((const float4*)(alog + (size_t)d * DST))[q];
        A[4 * q] = -__expf(v.x); A[4 * q + 1] = -__expf(v.y);
        A[4 * q + 2] = -__expf(v.z); A[4 * q + 3] = -__expf(v.w);
    }
    __shared__ float Bc[CL][DST], Cc[CL][DST];
    int m0 = b * SEQ + c * CL;
    for (int i = threadIdx.x; i < CL * DST; i += 256) {
        int nl = i / DST, s = i % DST;
        size_t row = (size_t)(m0 + nl) * EPROJ;
        Bc[nl][s] = xdbl[row + DTR + s];
        Cc[nl][s] = xdbl[row + DTR + DST + s];
    }
    __syncthreads();
    float h[DST];
    size_t base = (size_t)c * NBDS + ((size_t)(b * DIN + d)) * DST;
#pragma unroll
    for (int q = 0; q < 12; q++) {
        float4 v = ((const float4*)(carry + base))[q];
        h[4 * q] = v.x; h[4 * q + 1] = v.y; h[4 * q + 2] = v.z; h[4 * q + 3] = v.w;
    }
    float Dv = Dw[d];
    for (int nl = 0; nl < CL; nl++) {
        size_t m = m0 + nl;
        float dtv = dt[m * DIN + d];
        float uv = u[m * DIN + d];
        float dtu = dtv * uv;
        float y = 0.f;
#pragma unroll
        for (int s = 0; s < DST; s++) {
            float dA = __expf(dtv * A[s]);
            h[s] = fmaf(dA, h[s], dtu * Bc[nl][s]);
            y = fmaf(h[s], Cc[nl][s], y);
        }
        float yv = fmaf(uv, Dv, y);
        float zv = xz[m * (2 * DIN) + DIN + d];
        float sz = zv / (1.f + __expf(-zv));
        yc[m * DIN + d] = yv * sz;
    }
}

extern "C" void kernel_launch(void* const* d_in, const int* in_sizes, int n_in,
                              void* d_out, int out_size, void* d_ws, size_t ws_size,
                              hipStream_t stream) {
    const float* x     = (const float*)d_in[0];
    const float* lnw   = (const float*)d_in[1];
    const float* lnb   = (const float*)d_in[2];
    const float* w_in  = (const float*)d_in[3];   // (1024, 256)
    const float* cw    = (const float*)d_in[4];   // (512, 4)
    const float* cb    = (const float*)d_in[5];
    const float* w_xp  = (const float*)d_in[6];   // (112, 512)
    const float* dtw   = (const float*)d_in[7];   // (512, 16)
    const float* dtb   = (const float*)d_in[8];
    const float* alog  = (const float*)d_in[9];   // (512, 48)
    const float* Dw    = (const float*)d_in[10];
    const float* w_out = (const float*)d_in[11];  // (256, 512)

    float* ws = (float*)d_ws;
    float* xn   = ws;                        // 4096*256
    float* xz   = xn + (size_t)M * DIM;      // 4096*1024
    float* u    = xz + (size_t)M * 2 * DIN;  // 4096*512
    float* xdbl = u + (size_t)M * DIN;       // 4096*112
    float* dt   = xdbl + (size_t)M * EPROJ;  // 4096*512
    float* P    = dt + (size_t)M * DIN;      // 32*98304
    float* Hy   = P + (size_t)CH * NBDS;     // 32*98304 (reused as gated-y after pass2)
    size_t need = ((size_t)(Hy - ws) + (size_t)CH * NBDS) * sizeof(float); // ~64.8 MB
    if (ws_size < need) return;              // fail visibly (zeros) if ws too small
    float* yc = Hy;                          // gated y, 4096*512 fp32

    k_ln<<<M, 256, 0, stream>>>(x, lnw, lnb, xn);
    k_gemm_mfma<128, 128, 4, 4><<<dim3(M / 128, 1024 / 128), 256, 0, stream>>>(xn, w_in, xz, 256, 1024, 1024);
    k_conv<<<M * DIN / 256, 256, 0, stream>>>(xz, cw, cb, u);
    k_gemm_mfma<64, 128, 2, 4><<<dim3(M / 64, 1), 256, 0, stream>>>(u, w_xp, xdbl, 512, EPROJ, EPROJ);
    k_dt<<<M, 256, 0, stream>>>(xdbl, dtw, dtb, dt);
    k_scan1<<<dim3(BSZ * CH, 2), 256, 0, stream>>>(dt, u, xdbl, alog, P, Hy);
    k_scan2<<<NBDS / 256, 256, 0, stream>>>(P, Hy);
    k_scan3<<<dim3(BSZ * CH, 2), 256, 0, stream>>>(dt, u, xdbl, alog, P, xz, Dw, yc);
    k_gemm_mfma<64, 128, 2, 4><<<dim3(M / 64, 256 / 128), 256, 0, stream>>>(yc, w_out, (float*)d_out, 512, 256, 256);
}

// Round 8
// 176.859 us; speedup vs baseline: 2.3647x; 1.3869x over previous
//
#include <hip/hip_runtime.h>
#include <hip/hip_bf16.h>

// Mamba layer, MI355X. Inputs fp32; OUTPUT fp32. Internal math fp32.
// Round 8: GEMM grids enlarged (512 blocks each) via smaller M-tiles + split-K
// with fixup kernels (x_proj fixup fused with dt). Split-bf16 MFMA (hh+hl+lh).
// B=4 SEQ=1024 DIM=256 DIN=512 DST=48 DTR=16 E=112. M = B*SEQ = 4096 rows.

constexpr int BSZ = 4, SEQ = 1024, DIM = 256, DIN = 512, DST = 48, DTR = 16, EPROJ = 112;
constexpr int M = BSZ * SEQ;            // 4096
constexpr int CH = 32, CL = 32;         // 32 chunks x 32 steps = 1024
constexpr int NBDS = BSZ * DIN * DST;   // 98304 independent scan streams

using bfrag = __attribute__((ext_vector_type(8))) short;
using f32x4 = __attribute__((ext_vector_type(4))) float;
using us4   = __attribute__((ext_vector_type(4))) unsigned short;

static __device__ __forceinline__ unsigned short f2bf(float f) {
    union { float f; unsigned u; } v; v.f = f;
    unsigned r = v.u + 0x7fffu + ((v.u >> 16) & 1u);   // RTN-even
    return (unsigned short)(r >> 16);
}
static __device__ __forceinline__ float bf2f(unsigned short h) {
    union { unsigned u; float f; } v; v.u = (unsigned)h << 16;
    return v.f;
}

// ---------------- LayerNorm: x -> xn (fp32) ----------------
__global__ void k_ln(const float* __restrict__ x, const float* __restrict__ lnw,
                     const float* __restrict__ lnb, float* __restrict__ xn) {
    int m = blockIdx.x, t = threadIdx.x;     // 256 threads, one row per block
    float v = x[m * DIM + t];
    float s = v, s2 = v * v;
#pragma unroll
    for (int off = 32; off; off >>= 1) { s += __shfl_down(s, off); s2 += __shfl_down(s2, off); }
    __shared__ float ss[4], sq[4];
    int w = t >> 6;
    if ((t & 63) == 0) { ss[w] = s; sq[w] = s2; }
    __syncthreads();
    float tot = ss[0] + ss[1] + ss[2] + ss[3];
    float tq = sq[0] + sq[1] + sq[2] + sq[3];
    float mu = tot * (1.f / DIM);
    float var = tq * (1.f / DIM) - mu * mu;  // biased, matches jnp.var
    float rs = rsqrtf(var + 1e-5f);
    xn[m * DIM + t] = (v - mu) * rs * lnw[t] + lnb[t];
}

// ---------------- MFMA GEMM, split-bf16: out[m,n] = sum_k A[m,k]*W[n,k] ----------------
// A fp32 [Mtot][lda], W fp32 [Ntot][lda]. 256 threads = 4 waves in 2x2 grid.
// blockIdx.z = split-K slice (KSUB k-elems each); partial outputs stacked by z.
template <int BM, int BN, int FM, int FN, int KSUB>
__global__ __launch_bounds__(256, 1) void k_gemm_mfma(
    const float* __restrict__ A, const float* __restrict__ W,
    float* __restrict__ outp, int lda, int Nvalid, int ldo, int Mtot) {
    constexpr int BK = 32, BKP = 40;   // pad rows to 80B: 16B-aligned, uniform banks
    __shared__ __align__(16) unsigned short Ah[BM * BKP], Al[BM * BKP];
    __shared__ __align__(16) unsigned short Bh[BN * BKP], Bl[BN * BKP];
    const int tid = threadIdx.x;
    const int lane = tid & 63;
    const int w = tid >> 6;
    const int wm = w >> 1, wn = w & 1;
    const int bm0 = blockIdx.x * BM;
    const int bn0 = blockIdx.y * BN;
    const int kb = blockIdx.z * KSUB;
    float* out = outp + (size_t)blockIdx.z * Mtot * ldo;

    f32x4 acc[FM][FN];
#pragma unroll
    for (int i = 0; i < FM; i++)
#pragma unroll
        for (int j = 0; j < FN; j++) acc[i][j] = f32x4{0.f, 0.f, 0.f, 0.f};

    for (int k0 = kb; k0 < kb + KSUB; k0 += BK) {
        // ---- stage A tile (BM x 32 fp32 -> hi/lo bf16 planes) ----
        for (int flat = tid * 4; flat < BM * BK; flat += 1024) {
            int r = flat >> 5, c = flat & 31;
            float4 v = *(const float4*)(A + (size_t)(bm0 + r) * lda + k0 + c);
            us4 hi, lo;
            hi.x = f2bf(v.x); lo.x = f2bf(v.x - bf2f(hi.x));
            hi.y = f2bf(v.y); lo.y = f2bf(v.y - bf2f(hi.y));
            hi.z = f2bf(v.z); lo.z = f2bf(v.z - bf2f(hi.z));
            hi.w = f2bf(v.w); lo.w = f2bf(v.w - bf2f(hi.w));
            *(us4*)&Ah[r * BKP + c] = hi;
            *(us4*)&Al[r * BKP + c] = lo;
        }
        // ---- stage B tile (BN x 32 rows of W) ----
        for (int flat = tid * 4; flat < BN * BK; flat += 1024) {
            int r = flat >> 5, c = flat & 31;
            int gn = bn0 + r;
            float4 v = (gn < Nvalid) ? *(const float4*)(W + (size_t)gn * lda + k0 + c)
                                     : float4{0.f, 0.f, 0.f, 0.f};
            us4 hi, lo;
            hi.x = f2bf(v.x); lo.x = f2bf(v.x - bf2f(hi.x));
            hi.y = f2bf(v.y); lo.y = f2bf(v.y - bf2f(hi.y));
            hi.z = f2bf(v.z); lo.z = f2bf(v.z - bf2f(hi.z));
            hi.w = f2bf(v.w); lo.w = f2bf(v.w - bf2f(hi.w));
            *(us4*)&Bh[r * BKP + c] = hi;
            *(us4*)&Bl[r * BKP + c] = lo;
        }
        __syncthreads();

        // ---- fragment loads: lane&15 = row(col), (lane>>4)*8 = k offset ----
        const int kcol = (lane >> 4) * 8;
        const int rsel = lane & 15;
        bfrag afh[FM], afl[FM], bfh[FN], bfl[FN];
#pragma unroll
        for (int i = 0; i < FM; i++) {
            int row = wm * (FM * 16) + i * 16 + rsel;
            afh[i] = *(const bfrag*)&Ah[row * BKP + kcol];
            afl[i] = *(const bfrag*)&Al[row * BKP + kcol];
        }
#pragma unroll
        for (int j = 0; j < FN; j++) {
            int col = wn * (FN * 16) + j * 16 + rsel;
            bfh[j] = *(const bfrag*)&Bh[col * BKP + kcol];
            bfl[j] = *(const bfrag*)&Bl[col * BKP + kcol];
        }
#pragma unroll
        for (int i = 0; i < FM; i++)
#pragma unroll
            for (int j = 0; j < FN; j++) {
                acc[i][j] = __builtin_amdgcn_mfma_f32_16x16x32_bf16(afh[i], bfh[j], acc[i][j], 0, 0, 0);
                acc[i][j] = __builtin_amdgcn_mfma_f32_16x16x32_bf16(afh[i], bfl[j], acc[i][j], 0, 0, 0);
                acc[i][j] = __builtin_amdgcn_mfma_f32_16x16x32_bf16(afl[i], bfh[j], acc[i][j], 0, 0, 0);
            }
        __syncthreads();
    }

    // ---- epilogue: C/D layout col=lane&15, row=(lane>>4)*4+reg ----
    const int crow = (lane >> 4) * 4;
    const int ccol = lane & 15;
#pragma unroll
    for (int i = 0; i < FM; i++)
#pragma unroll
        for (int j = 0; j < FN; j++) {
            int gn = bn0 + wn * (FN * 16) + j * 16 + ccol;
            if (gn < Nvalid) {
                int gm = bm0 + wm * (FM * 16) + i * 16 + crow;
#pragma unroll
                for (int r = 0; r < 4; r++)
                    out[(size_t)(gm + r) * ldo + gn] = acc[i][j][r];
            }
        }
}

// ---------------- x_proj fixup (sum 4 partials) fused with dt ----------------
__global__ void k_fixdt(const float* __restrict__ part, const float* __restrict__ dtw,
                        const float* __restrict__ dtb, float* __restrict__ xdbl,
                        float* __restrict__ dt) {
    int m = blockIdx.x, t = threadIdx.x;
    __shared__ float r[DTR];
    constexpr size_t PS = (size_t)M * EPROJ;
    if (t < EPROJ) {
        size_t o = (size_t)m * EPROJ + t;
        float s = part[o] + part[PS + o] + part[2 * PS + o] + part[3 * PS + o];
        xdbl[o] = s;
        if (t < DTR) r[t] = s;
    }
    __syncthreads();
    for (int d = t; d < DIN; d += 256) {
        const float* wp = dtw + (size_t)d * DTR;
        float acc = dtb[d];
#pragma unroll
        for (int q = 0; q < DTR; q++) acc = fmaf(r[q], wp[q], acc);
        dt[(size_t)m * DIN + d] = (acc > 20.f) ? acc : log1pf(__expf(acc));
    }
}

// ---------------- out_proj fixup: d_out = p0 + p1 (float4) ----------------
__global__ void k_fix2(const float* __restrict__ part, float* __restrict__ out) {
    int i = blockIdx.x * 256 + threadIdx.x;       // float4 index
    constexpr size_t PS4 = (size_t)M * 256 / 4;   // 262144
    float4 a = ((const float4*)part)[i];
    float4 b = ((const float4*)part)[PS4 + i];
    ((float4*)out)[i] = make_float4(a.x + b.x, a.y + b.y, a.z + b.z, a.w + b.w);
}

// ---------------- causal depthwise conv(4) + bias + silu: xz[:, :512] -> u ----------------
__global__ void k_conv(const float* __restrict__ xz, const float* __restrict__ cw,
                       const float* __restrict__ cb, float* __restrict__ u) {
    int idx = blockIdx.x * 256 + threadIdx.x;     // [0, M*DIN)
    int d = idx & (DIN - 1);
    int m = idx >> 9;
    int n = m & (SEQ - 1);
    float4 w = *(const float4*)(cw + d * 4);
    float acc = cb[d] + xz[(size_t)m * (2 * DIN) + d] * w.w;
    if (n >= 1) acc += xz[(size_t)(m - 1) * (2 * DIN) + d] * w.z;
    if (n >= 2) acc += xz[(size_t)(m - 2) * (2 * DIN) + d] * w.y;
    if (n >= 3) acc += xz[(size_t)(m - 3) * (2 * DIN) + d] * w.x;
    u[idx] = acc / (1.f + __expf(-acc));          // silu
}

// ---------------- scan pass1: per-chunk (P = prod dA, H = local scan end) ----------------
__global__ __launch_bounds__(256, 1) void k_scan1(const float* __restrict__ dt, const float* __restrict__ u,
                                                  const float* __restrict__ xdbl, const float* __restrict__ alog,
                                                  float* __restrict__ P, float* __restrict__ H) {
    int c = blockIdx.x & (CH - 1), b = blockIdx.x >> 5;
    int d = blockIdx.y * 256 + threadIdx.x;
    float A[DST];
#pragma unroll
    for (int q = 0; q < 12; q++) {
        float4 v = ((const float4*)(alog + (size_t)d * DST))[q];
        A[4 * q] = -__expf(v.x); A[4 * q + 1] = -__expf(v.y);
        A[4 * q + 2] = -__expf(v.z); A[4 * q + 3] = -__expf(v.w);
    }
    __shared__ float Bc[CL][DST];
    int m0 = b * SEQ + c * CL;
    for (int i = threadIdx.x; i < CL * DST; i += 256)
        Bc[i / DST][i % DST] = xdbl[(size_t)(m0 + i / DST) * EPROJ + DTR + (i % DST)];
    __syncthreads();
    float Ps[DST], Hs[DST];
#pragma unroll
    for (int s = 0; s < DST; s++) { Ps[s] = 1.f; Hs[s] = 0.f; }
    for (int nl = 0; nl < CL; nl++) {
        size_t m = m0 + nl;
        float dtv = dt[m * DIN + d];
        float dtu = dtv * u[m * DIN + d];
#pragma unroll
        for (int s = 0; s < DST; s++) {
            float dA = __expf(dtv * A[s]);
            Ps[s] *= dA;
            Hs[s] = fmaf(dA, Hs[s], dtu * Bc[nl][s]);
        }
    }
    size_t base = (size_t)c * NBDS + ((size_t)(b * DIN + d)) * DST;
#pragma unroll
    for (int q = 0; q < 12; q++) {
        ((float4*)(P + base))[q] = make_float4(Ps[4 * q], Ps[4 * q + 1], Ps[4 * q + 2], Ps[4 * q + 3]);
        ((float4*)(H + base))[q] = make_float4(Hs[4 * q], Hs[4 * q + 1], Hs[4 * q + 2], Hs[4 * q + 3]);
    }
}

// ---------------- scan pass2: carry scan across chunks; P[c] := state BEFORE chunk c ----------------
__global__ void k_scan2(float* __restrict__ P, const float* __restrict__ H) {
    size_t idx = (size_t)blockIdx.x * 256 + threadIdx.x;   // [0, NBDS)
    float car = 0.f;
    for (int c = 0; c < CH; c++) {
        size_t o = (size_t)c * NBDS + idx;
        float p = P[o], h = H[o];
        P[o] = car;
        car = fmaf(p, car, h);
    }
}

// ---------------- scan pass3: replay chunk from carry, fuse +u*D and *silu(z) ----------------
__global__ __launch_bounds__(256, 1) void k_scan3(const float* __restrict__ dt, const float* __restrict__ u,
                                                  const float* __restrict__ xdbl, const float* __restrict__ alog,
                                                  const float* __restrict__ carry, const float* __restrict__ xz,
                                                  const float* __restrict__ Dw, float* __restrict__ yc) {
    int c = blockIdx.x & (CH - 1), b = blockIdx.x >> 5;
    int d = blockIdx.y * 256 + threadIdx.x;
    float A[DST];
#pragma unroll
    for (int q = 0; q < 12; q++) {
        float4 v = ((const float4*)(alog + (size_t)d * DST))[q];
        A[4 * q] = -__expf(v.x); A[4 * q + 1] = -__expf(v.y);
        A[4 * q + 2] = -__expf(v.z); A[4 * q + 3] = -__expf(v.w);
    }
    __shared__ float Bc[CL][DST], Cc[CL][DST];
    int m0 = b * SEQ + c * CL;
    for (int i = threadIdx.x; i < CL * DST; i += 256) {
        int nl = i / DST, s = i % DST;
        size_t row = (size_t)(m0 + nl) * EPROJ;
        Bc[nl][s] = xdbl[row + DTR + s];
        Cc[nl][s] = xdbl[row + DTR + DST + s];
    }
    __syncthreads();
    float h[DST];
    size_t base = (size_t)c * NBDS + ((size_t)(b * DIN + d)) * DST;
#pragma unroll
    for (int q = 0; q < 12; q++) {
        float4 v = ((const float4*)(carry + base))[q];
        h[4 * q] = v.x; h[4 * q + 1] = v.y; h[4 * q + 2] = v.z; h[4 * q + 3] = v.w;
    }
    float Dv = Dw[d];
    for (int nl = 0; nl < CL; nl++) {
        size_t m = m0 + nl;
        float dtv = dt[m * DIN + d];
        float uv = u[m * DIN + d];
        float dtu = dtv * uv;
        float y = 0.f;
#pragma unroll
        for (int s = 0; s < DST; s++) {
            float dA = __expf(dtv * A[s]);
            h[s] = fmaf(dA, h[s], dtu * Bc[nl][s]);
            y = fmaf(h[s], Cc[nl][s], y);
        }
        float yv = fmaf(uv, Dv, y);
        float zv = xz[m * (2 * DIN) + DIN + d];
        float sz = zv / (1.f + __expf(-zv));
        yc[m * DIN + d] = yv * sz;
    }
}

extern "C" void kernel_launch(void* const* d_in, const int* in_sizes, int n_in,
                              void* d_out, int out_size, void* d_ws, size_t ws_size,
                              hipStream_t stream) {
    const float* x     = (const float*)d_in[0];
    const float* lnw   = (const float*)d_in[1];
    const float* lnb   = (const float*)d_in[2];
    const float* w_in  = (const float*)d_in[3];   // (1024, 256)
    const float* cw    = (const float*)d_in[4];   // (512, 4)
    const float* cb    = (const float*)d_in[5];
    const float* w_xp  = (const float*)d_in[6];   // (112, 512)
    const float* dtw   = (const float*)d_in[7];   // (512, 16)
    const float* dtb   = (const float*)d_in[8];
    const float* alog  = (const float*)d_in[9];   // (512, 48)
    const float* Dw    = (const float*)d_in[10];
    const float* w_out = (const float*)d_in[11];  // (256, 512)

    float* ws = (float*)d_ws;
    float* xn      = ws;                          // 1,048,576
    float* xz      = xn + (size_t)M * DIM;        // 4,194,304
    float* u       = xz + (size_t)M * 2 * DIN;    // 2,097,152
    float* xdbl    = u + (size_t)M * DIN;         //   458,752
    float* dt      = xdbl + (size_t)M * EPROJ;    // 2,097,152
    float* scratch = dt + (size_t)M * DIN;        // 3,145,728 (xp_part | P/carry | op_part)
    float* Hy      = scratch + (size_t)CH * NBDS; // 3,145,728 (H | yc)
    size_t need = ((size_t)(Hy - ws) + (size_t)CH * NBDS) * sizeof(float); // ~64.75 MB
    if (ws_size < need) return;              // fail visibly (zeros) if ws too small
    float* yc = Hy;

    k_ln<<<M, 256, 0, stream>>>(x, lnw, lnb, xn);
    // in_proj: M=4096, N=1024, K=256 -> 512 blocks
    k_gemm_mfma<64, 128, 2, 4, 256><<<dim3(M / 64, 1024 / 128, 1), 256, 0, stream>>>(
        xn, w_in, xz, 256, 1024, 1024, M);
    k_conv<<<M * DIN / 256, 256, 0, stream>>>(xz, cw, cb, u);
    // x_proj: M=4096, N=112, K=512, split-K=4 -> 512 blocks, partials in scratch
    k_gemm_mfma<32, 128, 1, 4, 128><<<dim3(M / 32, 1, 4), 256, 0, stream>>>(
        u, w_xp, scratch, 512, EPROJ, EPROJ, M);
    k_fixdt<<<M, 256, 0, stream>>>(scratch, dtw, dtb, xdbl, dt);
    k_scan1<<<dim3(BSZ * CH, 2), 256, 0, stream>>>(dt, u, xdbl, alog, scratch, Hy);
    k_scan2<<<NBDS / 256, 256, 0, stream>>>(scratch, Hy);
    k_scan3<<<dim3(BSZ * CH, 2), 256, 0, stream>>>(dt, u, xdbl, alog, scratch, xz, Dw, yc);
    // out_proj: M=4096, N=256, K=512, split-K=2 -> 512 blocks, partials in scratch
    k_gemm_mfma<32, 128, 1, 4, 256><<<dim3(M / 32, 256 / 128, 2), 256, 0, stream>>>(
        yc, w_out, scratch, 512, 256, 256, M);
    k_fix2<<<(M * 256 / 4) / 256, 256, 0, stream>>>(scratch, (float*)d_out);
}

// Round 9
// 168.128 us; speedup vs baseline: 2.4875x; 1.0519x over previous
//
#include <hip/hip_runtime.h>
#include <hip/hip_bf16.h>

// Mamba layer, MI355X. Inputs fp32; OUTPUT fp32. Internal math fp32.
// Round 9: scan1/scan3 s-split x4 (12 states/thread, 4-thread squads per d)
// -> 1024 blocks (4/CU), ~50 VGPR. P/H layout & ws unchanged.
// B=4 SEQ=1024 DIM=256 DIN=512 DST=48 DTR=16 E=112. M = B*SEQ = 4096 rows.

constexpr int BSZ = 4, SEQ = 1024, DIM = 256, DIN = 512, DST = 48, DTR = 16, EPROJ = 112;
constexpr int M = BSZ * SEQ;            // 4096
constexpr int CH = 32, CL = 32;         // 32 chunks x 32 steps = 1024
constexpr int NBDS = BSZ * DIN * DST;   // 98304 independent scan streams

using bfrag = __attribute__((ext_vector_type(8))) short;
using f32x4 = __attribute__((ext_vector_type(4))) float;
using us4   = __attribute__((ext_vector_type(4))) unsigned short;

static __device__ __forceinline__ unsigned short f2bf(float f) {
    union { float f; unsigned u; } v; v.f = f;
    unsigned r = v.u + 0x7fffu + ((v.u >> 16) & 1u);   // RTN-even
    return (unsigned short)(r >> 16);
}
static __device__ __forceinline__ float bf2f(unsigned short h) {
    union { unsigned u; float f; } v; v.u = (unsigned)h << 16;
    return v.f;
}

// ---------------- LayerNorm: x -> xn (fp32) ----------------
__global__ void k_ln(const float* __restrict__ x, const float* __restrict__ lnw,
                     const float* __restrict__ lnb, float* __restrict__ xn) {
    int m = blockIdx.x, t = threadIdx.x;     // 256 threads, one row per block
    float v = x[m * DIM + t];
    float s = v, s2 = v * v;
#pragma unroll
    for (int off = 32; off; off >>= 1) { s += __shfl_down(s, off); s2 += __shfl_down(s2, off); }
    __shared__ float ss[4], sq[4];
    int w = t >> 6;
    if ((t & 63) == 0) { ss[w] = s; sq[w] = s2; }
    __syncthreads();
    float tot = ss[0] + ss[1] + ss[2] + ss[3];
    float tq = sq[0] + sq[1] + sq[2] + sq[3];
    float mu = tot * (1.f / DIM);
    float var = tq * (1.f / DIM) - mu * mu;  // biased, matches jnp.var
    float rs = rsqrtf(var + 1e-5f);
    xn[m * DIM + t] = (v - mu) * rs * lnw[t] + lnb[t];
}

// ---------------- MFMA GEMM, split-bf16: out[m,n] = sum_k A[m,k]*W[n,k] ----------------
template <int BM, int BN, int FM, int FN, int KSUB>
__global__ __launch_bounds__(256, 1) void k_gemm_mfma(
    const float* __restrict__ A, const float* __restrict__ W,
    float* __restrict__ outp, int lda, int Nvalid, int ldo, int Mtot) {
    constexpr int BK = 32, BKP = 40;   // pad rows to 80B: 16B-aligned, uniform banks
    __shared__ __align__(16) unsigned short Ah[BM * BKP], Al[BM * BKP];
    __shared__ __align__(16) unsigned short Bh[BN * BKP], Bl[BN * BKP];
    const int tid = threadIdx.x;
    const int lane = tid & 63;
    const int w = tid >> 6;
    const int wm = w >> 1, wn = w & 1;
    const int bm0 = blockIdx.x * BM;
    const int bn0 = blockIdx.y * BN;
    const int kb = blockIdx.z * KSUB;
    float* out = outp + (size_t)blockIdx.z * Mtot * ldo;

    f32x4 acc[FM][FN];
#pragma unroll
    for (int i = 0; i < FM; i++)
#pragma unroll
        for (int j = 0; j < FN; j++) acc[i][j] = f32x4{0.f, 0.f, 0.f, 0.f};

    for (int k0 = kb; k0 < kb + KSUB; k0 += BK) {
        for (int flat = tid * 4; flat < BM * BK; flat += 1024) {
            int r = flat >> 5, c = flat & 31;
            float4 v = *(const float4*)(A + (size_t)(bm0 + r) * lda + k0 + c);
            us4 hi, lo;
            hi.x = f2bf(v.x); lo.x = f2bf(v.x - bf2f(hi.x));
            hi.y = f2bf(v.y); lo.y = f2bf(v.y - bf2f(hi.y));
            hi.z = f2bf(v.z); lo.z = f2bf(v.z - bf2f(hi.z));
            hi.w = f2bf(v.w); lo.w = f2bf(v.w - bf2f(hi.w));
            *(us4*)&Ah[r * BKP + c] = hi;
            *(us4*)&Al[r * BKP + c] = lo;
        }
        for (int flat = tid * 4; flat < BN * BK; flat += 1024) {
            int r = flat >> 5, c = flat & 31;
            int gn = bn0 + r;
            float4 v = (gn < Nvalid) ? *(const float4*)(W + (size_t)gn * lda + k0 + c)
                                     : float4{0.f, 0.f, 0.f, 0.f};
            us4 hi, lo;
            hi.x = f2bf(v.x); lo.x = f2bf(v.x - bf2f(hi.x));
            hi.y = f2bf(v.y); lo.y = f2bf(v.y - bf2f(hi.y));
            hi.z = f2bf(v.z); lo.z = f2bf(v.z - bf2f(hi.z));
            hi.w = f2bf(v.w); lo.w = f2bf(v.w - bf2f(hi.w));
            *(us4*)&Bh[r * BKP + c] = hi;
            *(us4*)&Bl[r * BKP + c] = lo;
        }
        __syncthreads();

        const int kcol = (lane >> 4) * 8;
        const int rsel = lane & 15;
        bfrag afh[FM], afl[FM], bfh[FN], bfl[FN];
#pragma unroll
        for (int i = 0; i < FM; i++) {
            int row = wm * (FM * 16) + i * 16 + rsel;
            afh[i] = *(const bfrag*)&Ah[row * BKP + kcol];
            afl[i] = *(const bfrag*)&Al[row * BKP + kcol];
        }
#pragma unroll
        for (int j = 0; j < FN; j++) {
            int col = wn * (FN * 16) + j * 16 + rsel;
            bfh[j] = *(const bfrag*)&Bh[col * BKP + kcol];
            bfl[j] = *(const bfrag*)&Bl[col * BKP + kcol];
        }
#pragma unroll
        for (int i = 0; i < FM; i++)
#pragma unroll
            for (int j = 0; j < FN; j++) {
                acc[i][j] = __builtin_amdgcn_mfma_f32_16x16x32_bf16(afh[i], bfh[j], acc[i][j], 0, 0, 0);
                acc[i][j] = __builtin_amdgcn_mfma_f32_16x16x32_bf16(afh[i], bfl[j], acc[i][j], 0, 0, 0);
                acc[i][j] = __builtin_amdgcn_mfma_f32_16x16x32_bf16(afl[i], bfh[j], acc[i][j], 0, 0, 0);
            }
        __syncthreads();
    }

    const int crow = (lane >> 4) * 4;
    const int ccol = lane & 15;
#pragma unroll
    for (int i = 0; i < FM; i++)
#pragma unroll
        for (int j = 0; j < FN; j++) {
            int gn = bn0 + wn * (FN * 16) + j * 16 + ccol;
            if (gn < Nvalid) {
                int gm = bm0 + wm * (FM * 16) + i * 16 + crow;
#pragma unroll
                for (int r = 0; r < 4; r++)
                    out[(size_t)(gm + r) * ldo + gn] = acc[i][j][r];
            }
        }
}

// ---------------- x_proj fixup (sum 4 partials) fused with dt ----------------
__global__ void k_fixdt(const float* __restrict__ part, const float* __restrict__ dtw,
                        const float* __restrict__ dtb, float* __restrict__ xdbl,
                        float* __restrict__ dt) {
    int m = blockIdx.x, t = threadIdx.x;
    __shared__ float r[DTR];
    constexpr size_t PS = (size_t)M * EPROJ;
    if (t < EPROJ) {
        size_t o = (size_t)m * EPROJ + t;
        float s = part[o] + part[PS + o] + part[2 * PS + o] + part[3 * PS + o];
        xdbl[o] = s;
        if (t < DTR) r[t] = s;
    }
    __syncthreads();
    for (int d = t; d < DIN; d += 256) {
        const float* wp = dtw + (size_t)d * DTR;
        float acc = dtb[d];
#pragma unroll
        for (int q = 0; q < DTR; q++) acc = fmaf(r[q], wp[q], acc);
        dt[(size_t)m * DIN + d] = (acc > 20.f) ? acc : log1pf(__expf(acc));
    }
}

// ---------------- out_proj fixup: d_out = p0 + p1 (float4) ----------------
__global__ void k_fix2(const float* __restrict__ part, float* __restrict__ out) {
    int i = blockIdx.x * 256 + threadIdx.x;       // float4 index
    constexpr size_t PS4 = (size_t)M * 256 / 4;   // 262144
    float4 a = ((const float4*)part)[i];
    float4 b = ((const float4*)part)[PS4 + i];
    ((float4*)out)[i] = make_float4(a.x + b.x, a.y + b.y, a.z + b.z, a.w + b.w);
}

// ---------------- causal depthwise conv(4) + bias + silu: xz[:, :512] -> u ----------------
__global__ void k_conv(const float* __restrict__ xz, const float* __restrict__ cw,
                       const float* __restrict__ cb, float* __restrict__ u) {
    int idx = blockIdx.x * 256 + threadIdx.x;     // [0, M*DIN)
    int d = idx & (DIN - 1);
    int m = idx >> 9;
    int n = m & (SEQ - 1);
    float4 w = *(const float4*)(cw + d * 4);
    float acc = cb[d] + xz[(size_t)m * (2 * DIN) + d] * w.w;
    if (n >= 1) acc += xz[(size_t)(m - 1) * (2 * DIN) + d] * w.z;
    if (n >= 2) acc += xz[(size_t)(m - 2) * (2 * DIN) + d] * w.y;
    if (n >= 3) acc += xz[(size_t)(m - 3) * (2 * DIN) + d] * w.x;
    u[idx] = acc / (1.f + __expf(-acc));          // silu
}

// ---------------- scan pass1: s-split x4. thread=(d, squad); 12 states each ----------------
__global__ __launch_bounds__(256, 4) void k_scan1(const float* __restrict__ dt, const float* __restrict__ u,
                                                  const float* __restrict__ xdbl, const float* __restrict__ alog,
                                                  float* __restrict__ P, float* __restrict__ H) {
    int c = blockIdx.x & (CH - 1), b = blockIdx.x >> 5;
    int t = threadIdx.x;
    int d = blockIdx.y * 64 + (t >> 2);
    int sq = t & 3;                          // squad: states [12*sq, 12*sq+12)
    int s0 = sq * 12;
    float A[12];
#pragma unroll
    for (int q = 0; q < 3; q++) {
        float4 v = ((const float4*)(alog + (size_t)d * DST + s0))[q];
        A[4 * q] = -__expf(v.x); A[4 * q + 1] = -__expf(v.y);
        A[4 * q + 2] = -__expf(v.z); A[4 * q + 3] = -__expf(v.w);
    }
    __shared__ float Bc[CL][DST];
    int m0 = b * SEQ + c * CL;
    for (int i = t; i < CL * DST; i += 256)
        Bc[i / DST][i % DST] = xdbl[(size_t)(m0 + i / DST) * EPROJ + DTR + (i % DST)];
    __syncthreads();
    float Ps[12], Hs[12];
#pragma unroll
    for (int s = 0; s < 12; s++) { Ps[s] = 1.f; Hs[s] = 0.f; }
    for (int nl = 0; nl < CL; nl++) {
        size_t m = m0 + nl;
        float dtv = dt[m * DIN + d];
        float dtu = dtv * u[m * DIN + d];
#pragma unroll
        for (int s = 0; s < 12; s++) {
            float dA = __expf(dtv * A[s]);
            Ps[s] *= dA;
            Hs[s] = fmaf(dA, Hs[s], dtu * Bc[nl][s0 + s]);
        }
    }
    size_t base = (size_t)c * NBDS + ((size_t)(b * DIN + d)) * DST + s0;
#pragma unroll
    for (int q = 0; q < 3; q++) {
        ((float4*)(P + base))[q] = make_float4(Ps[4 * q], Ps[4 * q + 1], Ps[4 * q + 2], Ps[4 * q + 3]);
        ((float4*)(H + base))[q] = make_float4(Hs[4 * q], Hs[4 * q + 1], Hs[4 * q + 2], Hs[4 * q + 3]);
    }
}

// ---------------- scan pass2: carry scan across chunks; P[c] := state BEFORE chunk c ----------------
__global__ void k_scan2(float* __restrict__ P, const float* __restrict__ H) {
    size_t idx = (size_t)blockIdx.x * 256 + threadIdx.x;   // [0, NBDS)
    float car = 0.f;
    for (int c = 0; c < CH; c++) {
        size_t o = (size_t)c * NBDS + idx;
        float p = P[o], h = H[o];
        P[o] = car;
        car = fmaf(p, car, h);
    }
}

// ---------------- scan pass3: s-split x4; squad y-reduce via shfl; fuse +u*D, *silu(z) ----------------
__global__ __launch_bounds__(256, 4) void k_scan3(const float* __restrict__ dt, const float* __restrict__ u,
                                                  const float* __restrict__ xdbl, const float* __restrict__ alog,
                                                  const float* __restrict__ carry, const float* __restrict__ xz,
                                                  const float* __restrict__ Dw, float* __restrict__ yc) {
    int c = blockIdx.x & (CH - 1), b = blockIdx.x >> 5;
    int t = threadIdx.x;
    int d = blockIdx.y * 64 + (t >> 2);
    int sq = t & 3;
    int s0 = sq * 12;
    float A[12];
#pragma unroll
    for (int q = 0; q < 3; q++) {
        float4 v = ((const float4*)(alog + (size_t)d * DST + s0))[q];
        A[4 * q] = -__expf(v.x); A[4 * q + 1] = -__expf(v.y);
        A[4 * q + 2] = -__expf(v.z); A[4 * q + 3] = -__expf(v.w);
    }
    __shared__ float Bc[CL][DST], Cc[CL][DST];
    int m0 = b * SEQ + c * CL;
    for (int i = t; i < CL * DST; i += 256) {
        int nl = i / DST, s = i % DST;
        size_t row = (size_t)(m0 + nl) * EPROJ;
        Bc[nl][s] = xdbl[row + DTR + s];
        Cc[nl][s] = xdbl[row + DTR + DST + s];
    }
    __syncthreads();
    float h[12];
    size_t base = (size_t)c * NBDS + ((size_t)(b * DIN + d)) * DST + s0;
#pragma unroll
    for (int q = 0; q < 3; q++) {
        float4 v = ((const float4*)(carry + base))[q];
        h[4 * q] = v.x; h[4 * q + 1] = v.y; h[4 * q + 2] = v.z; h[4 * q + 3] = v.w;
    }
    float Dv = Dw[d];
    for (int nl = 0; nl < CL; nl++) {
        size_t m = m0 + nl;
        float dtv = dt[m * DIN + d];
        float uv = u[m * DIN + d];
        float dtu = dtv * uv;
        float y = 0.f;
#pragma unroll
        for (int s = 0; s < 12; s++) {
            float dA = __expf(dtv * A[s]);
            h[s] = fmaf(dA, h[s], dtu * Bc[nl][s0 + s]);
            y = fmaf(h[s], Cc[nl][s0 + s], y);
        }
        y += __shfl_xor(y, 1);
        y += __shfl_xor(y, 2);
        if (sq == 0) {
            float yv = fmaf(uv, Dv, y);
            float zv = xz[m * (2 * DIN) + DIN + d];
            float sz = zv / (1.f + __expf(-zv));
            yc[m * DIN + d] = yv * sz;
        }
    }
}

extern "C" void kernel_launch(void* const* d_in, const int* in_sizes, int n_in,
                              void* d_out, int out_size, void* d_ws, size_t ws_size,
                              hipStream_t stream) {
    const float* x     = (const float*)d_in[0];
    const float* lnw   = (const float*)d_in[1];
    const float* lnb   = (const float*)d_in[2];
    const float* w_in  = (const float*)d_in[3];   // (1024, 256)
    const float* cw    = (const float*)d_in[4];   // (512, 4)
    const float* cb    = (const float*)d_in[5];
    const float* w_xp  = (const float*)d_in[6];   // (112, 512)
    const float* dtw   = (const float*)d_in[7];   // (512, 16)
    const float* dtb   = (const float*)d_in[8];
    const float* alog  = (const float*)d_in[9];   // (512, 48)
    const float* Dw    = (const float*)d_in[10];
    const float* w_out = (const float*)d_in[11];  // (256, 512)

    float* ws = (float*)d_ws;
    float* xn      = ws;                          // 1,048,576
    float* xz      = xn + (size_t)M * DIM;        // 4,194,304
    float* u       = xz + (size_t)M * 2 * DIN;    // 2,097,152
    float* xdbl    = u + (size_t)M * DIN;         //   458,752
    float* dt      = xdbl + (size_t)M * EPROJ;    // 2,097,152
    float* scratch = dt + (size_t)M * DIN;        // 3,145,728 (xp_part | P/carry | op_part)
    float* Hy      = scratch + (size_t)CH * NBDS; // 3,145,728 (H | yc)
    size_t need = ((size_t)(Hy - ws) + (size_t)CH * NBDS) * sizeof(float); // ~64.75 MB
    if (ws_size < need) return;              // fail visibly (zeros) if ws too small
    float* yc = Hy;

    k_ln<<<M, 256, 0, stream>>>(x, lnw, lnb, xn);
    // in_proj: M=4096, N=1024, K=256 -> 512 blocks
    k_gemm_mfma<64, 128, 2, 4, 256><<<dim3(M / 64, 1024 / 128, 1), 256, 0, stream>>>(
        xn, w_in, xz, 256, 1024, 1024, M);
    k_conv<<<M * DIN / 256, 256, 0, stream>>>(xz, cw, cb, u);
    // x_proj: M=4096, N=112, K=512, split-K=4 -> 512 blocks, partials in scratch
    k_gemm_mfma<32, 128, 1, 4, 128><<<dim3(M / 32, 1, 4), 256, 0, stream>>>(
        u, w_xp, scratch, 512, EPROJ, EPROJ, M);
    k_fixdt<<<M, 256, 0, stream>>>(scratch, dtw, dtb, xdbl, dt);
    k_scan1<<<dim3(BSZ * CH, 8), 256, 0, stream>>>(dt, u, xdbl, alog, scratch, Hy);
    k_scan2<<<NBDS / 256, 256, 0, stream>>>(scratch, Hy);
    k_scan3<<<dim3(BSZ * CH, 8), 256, 0, stream>>>(dt, u, xdbl, alog, scratch, xz, Dw, yc);
    // out_proj: M=4096, N=256, K=512, split-K=2 -> 512 blocks, partials in scratch
    k_gemm_mfma<32, 128, 1, 4, 256><<<dim3(M / 32, 256 / 128, 2), 256, 0, stream>>>(
        yc, w_out, scratch, 512, 256, 256, M);
    k_fix2<<<(M * 256 / 4) / 256, 256, 0, stream>>>(scratch, (float*)d_out);
}

// Round 10
// 146.315 us; speedup vs baseline: 2.8584x; 1.1491x over previous
//
#include <hip/hip_runtime.h>
#include <hip/hip_bf16.h>

// Mamba layer, MI355X. Inputs fp32; OUTPUT fp32. Internal math fp32.
// Round 10: scan1/scan3 — geometric-dA fast path (A[s]=-(s+1), runtime-guarded),
// telescoped P=exp(A*sum_dt), LDS-staged dt/u tiles. Rest unchanged.
// B=4 SEQ=1024 DIM=256 DIN=512 DST=48 DTR=16 E=112. M = B*SEQ = 4096 rows.

constexpr int BSZ = 4, SEQ = 1024, DIM = 256, DIN = 512, DST = 48, DTR = 16, EPROJ = 112;
constexpr int M = BSZ * SEQ;            // 4096
constexpr int CH = 32, CL = 32;         // 32 chunks x 32 steps = 1024
constexpr int NBDS = BSZ * DIN * DST;   // 98304 independent scan streams

using bfrag = __attribute__((ext_vector_type(8))) short;
using f32x4 = __attribute__((ext_vector_type(4))) float;
using us4   = __attribute__((ext_vector_type(4))) unsigned short;

static __device__ __forceinline__ unsigned short f2bf(float f) {
    union { float f; unsigned u; } v; v.f = f;
    unsigned r = v.u + 0x7fffu + ((v.u >> 16) & 1u);   // RTN-even
    return (unsigned short)(r >> 16);
}
static __device__ __forceinline__ float bf2f(unsigned short h) {
    union { unsigned u; float f; } v; v.u = (unsigned)h << 16;
    return v.f;
}

// ---------------- LayerNorm: x -> xn (fp32) ----------------
__global__ void k_ln(const float* __restrict__ x, const float* __restrict__ lnw,
                     const float* __restrict__ lnb, float* __restrict__ xn) {
    int m = blockIdx.x, t = threadIdx.x;     // 256 threads, one row per block
    float v = x[m * DIM + t];
    float s = v, s2 = v * v;
#pragma unroll
    for (int off = 32; off; off >>= 1) { s += __shfl_down(s, off); s2 += __shfl_down(s2, off); }
    __shared__ float ss[4], sq[4];
    int w = t >> 6;
    if ((t & 63) == 0) { ss[w] = s; sq[w] = s2; }
    __syncthreads();
    float tot = ss[0] + ss[1] + ss[2] + ss[3];
    float tq = sq[0] + sq[1] + sq[2] + sq[3];
    float mu = tot * (1.f / DIM);
    float var = tq * (1.f / DIM) - mu * mu;  // biased, matches jnp.var
    float rs = rsqrtf(var + 1e-5f);
    xn[m * DIM + t] = (v - mu) * rs * lnw[t] + lnb[t];
}

// ---------------- MFMA GEMM, split-bf16: out[m,n] = sum_k A[m,k]*W[n,k] ----------------
template <int BM, int BN, int FM, int FN, int KSUB>
__global__ __launch_bounds__(256, 1) void k_gemm_mfma(
    const float* __restrict__ A, const float* __restrict__ W,
    float* __restrict__ outp, int lda, int Nvalid, int ldo, int Mtot) {
    constexpr int BK = 32, BKP = 40;   // pad rows to 80B: 16B-aligned, uniform banks
    __shared__ __align__(16) unsigned short Ah[BM * BKP], Al[BM * BKP];
    __shared__ __align__(16) unsigned short Bh[BN * BKP], Bl[BN * BKP];
    const int tid = threadIdx.x;
    const int lane = tid & 63;
    const int w = tid >> 6;
    const int wm = w >> 1, wn = w & 1;
    const int bm0 = blockIdx.x * BM;
    const int bn0 = blockIdx.y * BN;
    const int kb = blockIdx.z * KSUB;
    float* out = outp + (size_t)blockIdx.z * Mtot * ldo;

    f32x4 acc[FM][FN];
#pragma unroll
    for (int i = 0; i < FM; i++)
#pragma unroll
        for (int j = 0; j < FN; j++) acc[i][j] = f32x4{0.f, 0.f, 0.f, 0.f};

    for (int k0 = kb; k0 < kb + KSUB; k0 += BK) {
        for (int flat = tid * 4; flat < BM * BK; flat += 1024) {
            int r = flat >> 5, c = flat & 31;
            float4 v = *(const float4*)(A + (size_t)(bm0 + r) * lda + k0 + c);
            us4 hi, lo;
            hi.x = f2bf(v.x); lo.x = f2bf(v.x - bf2f(hi.x));
            hi.y = f2bf(v.y); lo.y = f2bf(v.y - bf2f(hi.y));
            hi.z = f2bf(v.z); lo.z = f2bf(v.z - bf2f(hi.z));
            hi.w = f2bf(v.w); lo.w = f2bf(v.w - bf2f(hi.w));
            *(us4*)&Ah[r * BKP + c] = hi;
            *(us4*)&Al[r * BKP + c] = lo;
        }
        for (int flat = tid * 4; flat < BN * BK; flat += 1024) {
            int r = flat >> 5, c = flat & 31;
            int gn = bn0 + r;
            float4 v = (gn < Nvalid) ? *(const float4*)(W + (size_t)gn * lda + k0 + c)
                                     : float4{0.f, 0.f, 0.f, 0.f};
            us4 hi, lo;
            hi.x = f2bf(v.x); lo.x = f2bf(v.x - bf2f(hi.x));
            hi.y = f2bf(v.y); lo.y = f2bf(v.y - bf2f(hi.y));
            hi.z = f2bf(v.z); lo.z = f2bf(v.z - bf2f(hi.z));
            hi.w = f2bf(v.w); lo.w = f2bf(v.w - bf2f(hi.w));
            *(us4*)&Bh[r * BKP + c] = hi;
            *(us4*)&Bl[r * BKP + c] = lo;
        }
        __syncthreads();

        const int kcol = (lane >> 4) * 8;
        const int rsel = lane & 15;
        bfrag afh[FM], afl[FM], bfh[FN], bfl[FN];
#pragma unroll
        for (int i = 0; i < FM; i++) {
            int row = wm * (FM * 16) + i * 16 + rsel;
            afh[i] = *(const bfrag*)&Ah[row * BKP + kcol];
            afl[i] = *(const bfrag*)&Al[row * BKP + kcol];
        }
#pragma unroll
        for (int j = 0; j < FN; j++) {
            int col = wn * (FN * 16) + j * 16 + rsel;
            bfh[j] = *(const bfrag*)&Bh[col * BKP + kcol];
            bfl[j] = *(const bfrag*)&Bl[col * BKP + kcol];
        }
#pragma unroll
        for (int i = 0; i < FM; i++)
#pragma unroll
            for (int j = 0; j < FN; j++) {
                acc[i][j] = __builtin_amdgcn_mfma_f32_16x16x32_bf16(afh[i], bfh[j], acc[i][j], 0, 0, 0);
                acc[i][j] = __builtin_amdgcn_mfma_f32_16x16x32_bf16(afh[i], bfl[j], acc[i][j], 0, 0, 0);
                acc[i][j] = __builtin_amdgcn_mfma_f32_16x16x32_bf16(afl[i], bfh[j], acc[i][j], 0, 0, 0);
            }
        __syncthreads();
    }

    const int crow = (lane >> 4) * 4;
    const int ccol = lane & 15;
#pragma unroll
    for (int i = 0; i < FM; i++)
#pragma unroll
        for (int j = 0; j < FN; j++) {
            int gn = bn0 + wn * (FN * 16) + j * 16 + ccol;
            if (gn < Nvalid) {
                int gm = bm0 + wm * (FM * 16) + i * 16 + crow;
#pragma unroll
                for (int r = 0; r < 4; r++)
                    out[(size_t)(gm + r) * ldo + gn] = acc[i][j][r];
            }
        }
}

// ---------------- x_proj fixup (sum 4 partials) fused with dt ----------------
__global__ void k_fixdt(const float* __restrict__ part, const float* __restrict__ dtw,
                        const float* __restrict__ dtb, float* __restrict__ xdbl,
                        float* __restrict__ dt) {
    int m = blockIdx.x, t = threadIdx.x;
    __shared__ float r[DTR];
    constexpr size_t PS = (size_t)M * EPROJ;
    if (t < EPROJ) {
        size_t o = (size_t)m * EPROJ + t;
        float s = part[o] + part[PS + o] + part[2 * PS + o] + part[3 * PS + o];
        xdbl[o] = s;
        if (t < DTR) r[t] = s;
    }
    __syncthreads();
    for (int d = t; d < DIN; d += 256) {
        const float* wp = dtw + (size_t)d * DTR;
        float acc = dtb[d];
#pragma unroll
        for (int q = 0; q < DTR; q++) acc = fmaf(r[q], wp[q], acc);
        dt[(size_t)m * DIN + d] = (acc > 20.f) ? acc : log1pf(__expf(acc));
    }
}

// ---------------- out_proj fixup: d_out = p0 + p1 (float4) ----------------
__global__ void k_fix2(const float* __restrict__ part, float* __restrict__ out) {
    int i = blockIdx.x * 256 + threadIdx.x;       // float4 index
    constexpr size_t PS4 = (size_t)M * 256 / 4;   // 262144
    float4 a = ((const float4*)part)[i];
    float4 b = ((const float4*)part)[PS4 + i];
    ((float4*)out)[i] = make_float4(a.x + b.x, a.y + b.y, a.z + b.z, a.w + b.w);
}

// ---------------- causal depthwise conv(4) + bias + silu: xz[:, :512] -> u ----------------
__global__ void k_conv(const float* __restrict__ xz, const float* __restrict__ cw,
                       const float* __restrict__ cb, float* __restrict__ u) {
    int idx = blockIdx.x * 256 + threadIdx.x;     // [0, M*DIN)
    int d = idx & (DIN - 1);
    int m = idx >> 9;
    int n = m & (SEQ - 1);
    float4 w = *(const float4*)(cw + d * 4);
    float acc = cb[d] + xz[(size_t)m * (2 * DIN) + d] * w.w;
    if (n >= 1) acc += xz[(size_t)(m - 1) * (2 * DIN) + d] * w.z;
    if (n >= 2) acc += xz[(size_t)(m - 2) * (2 * DIN) + d] * w.y;
    if (n >= 3) acc += xz[(size_t)(m - 3) * (2 * DIN) + d] * w.x;
    u[idx] = acc / (1.f + __expf(-acc));          // silu
}

// ---------------- scan pass1: s-split x4, LDS-staged dt/u, geometric fast path ----------------
__global__ __launch_bounds__(256, 4) void k_scan1(const float* __restrict__ dt, const float* __restrict__ u,
                                                  const float* __restrict__ xdbl, const float* __restrict__ alog,
                                                  float* __restrict__ P, float* __restrict__ H) {
    int c = blockIdx.x & (CH - 1), b = blockIdx.x >> 5;
    int t = threadIdx.x;
    int dloc = t >> 2;
    int d = blockIdx.y * 64 + dloc;
    int sq = t & 3, s0 = sq * 12;
    float A[12];
    bool geo = true;
#pragma unroll
    for (int q = 0; q < 3; q++) {
        float4 v = ((const float4*)(alog + (size_t)d * DST + s0))[q];
        A[4 * q] = -__expf(v.x); A[4 * q + 1] = -__expf(v.y);
        A[4 * q + 2] = -__expf(v.z); A[4 * q + 3] = -__expf(v.w);
    }
#pragma unroll
    for (int s = 0; s < 12; s++) {
        float expect = (float)(s0 + s + 1);
        if (fabsf(A[s] + expect) > 1e-3f * expect) geo = false;
    }
    __shared__ float dts[CL][64], us[CL][64], Bc[CL][DST];
    int m0 = b * SEQ + c * CL;
    for (int i = t; i < 512; i += 256) {               // 32 rows x 16 float4
        int nl = i >> 4, c4 = (i & 15) * 4;
        size_t g = (size_t)(m0 + nl) * DIN + blockIdx.y * 64 + c4;
        *(float4*)&dts[nl][c4] = *(const float4*)(dt + g);
        *(float4*)&us[nl][c4]  = *(const float4*)(u + g);
    }
    for (int i = t; i < 384; i += 256) {               // 32 rows x 12 float4
        int nl = i / 12, c4 = (i % 12) * 4;
        *(float4*)&Bc[nl][c4] = *(const float4*)(xdbl + (size_t)(m0 + nl) * EPROJ + DTR + c4);
    }
    __syncthreads();
    float Hs[12], S = 0.f;
#pragma unroll
    for (int s = 0; s < 12; s++) Hs[s] = 0.f;
    if (geo) {
        for (int nl = 0; nl < CL; nl++) {
            float dtv = dts[nl][dloc];
            float dtu = dtv * us[nl][dloc];
            S += dtv;
            float r = __expf(-dtv);
            float dA = __expf(dtv * A[0]);             // r^(s0+1)
#pragma unroll
            for (int s = 0; s < 12; s++) {
                Hs[s] = fmaf(dA, Hs[s], dtu * Bc[nl][s0 + s]);
                dA *= r;
            }
        }
    } else {
        for (int nl = 0; nl < CL; nl++) {
            float dtv = dts[nl][dloc];
            float dtu = dtv * us[nl][dloc];
            S += dtv;
#pragma unroll
            for (int s = 0; s < 12; s++)
                Hs[s] = fmaf(__expf(dtv * A[s]), Hs[s], dtu * Bc[nl][s0 + s]);
        }
    }
    size_t base = (size_t)c * NBDS + ((size_t)(b * DIN + d)) * DST + s0;
#pragma unroll
    for (int q = 0; q < 3; q++) {
        // P (chunk product) = exp(A*S) exactly (telescoped) — valid for any A
        ((float4*)(P + base))[q] = make_float4(__expf(S * A[4 * q]), __expf(S * A[4 * q + 1]),
                                               __expf(S * A[4 * q + 2]), __expf(S * A[4 * q + 3]));
        ((float4*)(H + base))[q] = make_float4(Hs[4 * q], Hs[4 * q + 1], Hs[4 * q + 2], Hs[4 * q + 3]);
    }
}

// ---------------- scan pass2: carry scan across chunks; P[c] := state BEFORE chunk c ----------------
__global__ void k_scan2(float* __restrict__ P, const float* __restrict__ H) {
    size_t idx = (size_t)blockIdx.x * 256 + threadIdx.x;   // [0, NBDS)
    float car = 0.f;
    for (int c = 0; c < CH; c++) {
        size_t o = (size_t)c * NBDS + idx;
        float p = P[o], h = H[o];
        P[o] = car;
        car = fmaf(p, car, h);
    }
}

// ---------------- scan pass3: s-split x4, LDS-staged, geometric fast path ----------------
__global__ __launch_bounds__(256, 4) void k_scan3(const float* __restrict__ dt, const float* __restrict__ u,
                                                  const float* __restrict__ xdbl, const float* __restrict__ alog,
                                                  const float* __restrict__ carry, const float* __restrict__ xz,
                                                  const float* __restrict__ Dw, float* __restrict__ yc) {
    int c = blockIdx.x & (CH - 1), b = blockIdx.x >> 5;
    int t = threadIdx.x;
    int dloc = t >> 2;
    int d = blockIdx.y * 64 + dloc;
    int sq = t & 3, s0 = sq * 12;
    float A[12];
    bool geo = true;
#pragma unroll
    for (int q = 0; q < 3; q++) {
        float4 v = ((const float4*)(alog + (size_t)d * DST + s0))[q];
        A[4 * q] = -__expf(v.x); A[4 * q + 1] = -__expf(v.y);
        A[4 * q + 2] = -__expf(v.z); A[4 * q + 3] = -__expf(v.w);
    }
#pragma unroll
    for (int s = 0; s < 12; s++) {
        float expect = (float)(s0 + s + 1);
        if (fabsf(A[s] + expect) > 1e-3f * expect) geo = false;
    }
    __shared__ float dts[CL][64], us[CL][64], Bc[CL][DST], Cc[CL][DST];
    int m0 = b * SEQ + c * CL;
    for (int i = t; i < 512; i += 256) {
        int nl = i >> 4, c4 = (i & 15) * 4;
        size_t g = (size_t)(m0 + nl) * DIN + blockIdx.y * 64 + c4;
        *(float4*)&dts[nl][c4] = *(const float4*)(dt + g);
        *(float4*)&us[nl][c4]  = *(const float4*)(u + g);
    }
    for (int i = t; i < 768; i += 256) {
        int nl = (i >> 1) / 12, half = i & 1, c4 = ((i >> 1) % 12) * 4;
        size_t row = (size_t)(m0 + nl) * EPROJ + DTR;
        if (half == 0) *(float4*)&Bc[nl][c4] = *(const float4*)(xdbl + row + c4);
        else           *(float4*)&Cc[nl][c4] = *(const float4*)(xdbl + row + DST + c4);
    }
    __syncthreads();
    float h[12];
    size_t base = (size_t)c * NBDS + ((size_t)(b * DIN + d)) * DST + s0;
#pragma unroll
    for (int q = 0; q < 3; q++) {
        float4 v = ((const float4*)(carry + base))[q];
        h[4 * q] = v.x; h[4 * q + 1] = v.y; h[4 * q + 2] = v.z; h[4 * q + 3] = v.w;
    }
    float Dv = Dw[d];
    for (int nl = 0; nl < CL; nl++) {
        float dtv = dts[nl][dloc];
        float uv = us[nl][dloc];
        float dtu = dtv * uv;
        float y = 0.f;
        if (geo) {
            float r = __expf(-dtv);
            float dA = __expf(dtv * A[0]);
#pragma unroll
            for (int s = 0; s < 12; s++) {
                h[s] = fmaf(dA, h[s], dtu * Bc[nl][s0 + s]);
                y = fmaf(h[s], Cc[nl][s0 + s], y);
                dA *= r;
            }
        } else {
#pragma unroll
            for (int s = 0; s < 12; s++) {
                h[s] = fmaf(__expf(dtv * A[s]), h[s], dtu * Bc[nl][s0 + s]);
                y = fmaf(h[s], Cc[nl][s0 + s], y);
            }
        }
        y += __shfl_xor(y, 1);
        y += __shfl_xor(y, 2);
        if (sq == 0) {
            size_t m = m0 + nl;
            float yv = fmaf(uv, Dv, y);
            float zv = xz[m * (2 * DIN) + DIN + d];
            float sz = zv / (1.f + __expf(-zv));
            yc[m * DIN + d] = yv * sz;
        }
    }
}

extern "C" void kernel_launch(void* const* d_in, const int* in_sizes, int n_in,
                              void* d_out, int out_size, void* d_ws, size_t ws_size,
                              hipStream_t stream) {
    const float* x     = (const float*)d_in[0];
    const float* lnw   = (const float*)d_in[1];
    const float* lnb   = (const float*)d_in[2];
    const float* w_in  = (const float*)d_in[3];   // (1024, 256)
    const float* cw    = (const float*)d_in[4];   // (512, 4)
    const float* cb    = (const float*)d_in[5];
    const float* w_xp  = (const float*)d_in[6];   // (112, 512)
    const float* dtw   = (const float*)d_in[7];   // (512, 16)
    const float* dtb   = (const float*)d_in[8];
    const float* alog  = (const float*)d_in[9];   // (512, 48)
    const float* Dw    = (const float*)d_in[10];
    const float* w_out = (const float*)d_in[11];  // (256, 512)

    float* ws = (float*)d_ws;
    float* xn      = ws;                          // 1,048,576
    float* xz      = xn + (size_t)M * DIM;        // 4,194,304
    float* u       = xz + (size_t)M * 2 * DIN;    // 2,097,152
    float* xdbl    = u + (size_t)M * DIN;         //   458,752
    float* dt      = xdbl + (size_t)M * EPROJ;    // 2,097,152
    float* scratch = dt + (size_t)M * DIN;        // 3,145,728 (xp_part | P/carry | op_part)
    float* Hy      = scratch + (size_t)CH * NBDS; // 3,145,728 (H | yc)
    size_t need = ((size_t)(Hy - ws) + (size_t)CH * NBDS) * sizeof(float); // ~64.75 MB
    if (ws_size < need) return;              // fail visibly (zeros) if ws too small
    float* yc = Hy;

    k_ln<<<M, 256, 0, stream>>>(x, lnw, lnb, xn);
    // in_proj: M=4096, N=1024, K=256 -> 512 blocks
    k_gemm_mfma<64, 128, 2, 4, 256><<<dim3(M / 64, 1024 / 128, 1), 256, 0, stream>>>(
        xn, w_in, xz, 256, 1024, 1024, M);
    k_conv<<<M * DIN / 256, 256, 0, stream>>>(xz, cw, cb, u);
    // x_proj: M=4096, N=112, K=512, split-K=4 -> 512 blocks, partials in scratch
    k_gemm_mfma<32, 128, 1, 4, 128><<<dim3(M / 32, 1, 4), 256, 0, stream>>>(
        u, w_xp, scratch, 512, EPROJ, EPROJ, M);
    k_fixdt<<<M, 256, 0, stream>>>(scratch, dtw, dtb, xdbl, dt);
    k_scan1<<<dim3(BSZ * CH, 8), 256, 0, stream>>>(dt, u, xdbl, alog, scratch, Hy);
    k_scan2<<<NBDS / 256, 256, 0, stream>>>(scratch, Hy);
    k_scan3<<<dim3(BSZ * CH, 8), 256, 0, stream>>>(dt, u, xdbl, alog, scratch, xz, Dw, yc);
    // out_proj: M=4096, N=256, K=512, split-K=2 -> 512 blocks, partials in scratch
    k_gemm_mfma<32, 128, 1, 4, 256><<<dim3(M / 32, 256 / 128, 2), 256, 0, stream>>>(
        yc, w_out, scratch, 512, 256, 256, M);
    k_fix2<<<(M * 256 / 4) / 256, 256, 0, stream>>>(scratch, (float*)d_out);
}